// Round 9
// baseline (231.330 us; speedup 1.0000x reference)
//
#include <hip/hip_runtime.h>
#include <hip/hip_bf16.h>
#include <hip/hip_fp16.h>
#include <stdint.h>

#define V_  5
#define B_  2
#define C_  32
#define H_  128
#define W_  160
#define D_  32
#define G_  8
#define HW_  (H_*W_)
#define DHW_ (D_*HW_)

#define LOG2E_ 1.4426950408889634f
#define LN2_   0.6931471805599453f
#define LN8_   2.0794415416798357f

typedef _Float16 h8 __attribute__((ext_vector_type(8)));
typedef _Float16 h4 __attribute__((ext_vector_type(4)));
typedef _Float16 h2 __attribute__((ext_vector_type(2)));
typedef float    f4 __attribute__((ext_vector_type(4)));

__device__ inline float fdot2f(h2 a, h2 b, float c) {
#if __has_builtin(__builtin_amdgcn_fdot2)
    return __builtin_amdgcn_fdot2(a, b, c, false);
#else
    return fmaf((float)a[0], (float)b[0], fmaf((float)a[1], (float)b[1], c));
#endif
}

// ws layout (floats):
//  [0..95]      proj
//  [128..1151]  mlp sigmoid table
//  [1152..3455] wh1 fp16 [36][16][8]  (slot=(dz*3+hy)*4+wx, wx==3 zero)
//  [3456..3599] wh2 fp16 [36][8]      (m==0 row only)
//  [4736 ..]    featT fp16 (13.1MB, dead after k_main) / hidh fp16 (21MB)
//  [4736+5242880 ..] simh fp16 (21MB)

__device__ inline void combine_mat(const float* m, float out[4][4]) {
    const float* ext = m;
    const float* K   = m + 16;
    for (int r = 0; r < 4; ++r)
        for (int c = 0; c < 4; ++c)
            out[r][c] = ext[r*4 + c];
    for (int r = 0; r < 3; ++r)
        for (int c = 0; c < 4; ++c) {
            float s = 0.f;
            for (int k = 0; k < 3; ++k) s += K[r*4 + k] * ext[k*4 + c];
            out[r][c] = s;
        }
}

__device__ inline void invert4(const float Ain[4][4], float Inv[4][4]) {
    float A[4][4];
    for (int r = 0; r < 4; ++r)
        for (int c = 0; c < 4; ++c) {
            A[r][c]   = Ain[r][c];
            Inv[r][c] = (r == c) ? 1.f : 0.f;
        }
    for (int k = 0; k < 4; ++k) {
        int p = k; float best = fabsf(A[k][k]);
        for (int r = k + 1; r < 4; ++r) {
            float v = fabsf(A[r][k]);
            if (v > best) { best = v; p = r; }
        }
        if (p != k) {
            for (int j = 0; j < 4; ++j) {
                float t = A[k][j]; A[k][j] = A[p][j]; A[p][j] = t;
                t = Inv[k][j]; Inv[k][j] = Inv[p][j]; Inv[p][j] = t;
            }
        }
        float dinv = 1.f / A[k][k];
        for (int j = 0; j < 4; ++j) { A[k][j] *= dinv; Inv[k][j] *= dinv; }
        for (int r = 0; r < 4; ++r) {
            if (r == k) continue;
            float f = A[r][k];
            for (int j = 0; j < 4; ++j) {
                A[r][j]  -= f * A[k][j];
                Inv[r][j] -= f * Inv[k][j];
            }
        }
    }
}

// ---------------- feature transpose (+ fused proj/table/weight-pack on block 0) ----------------
// [V][B][C][H][W] f32 -> [VB][HW][C] fp16
__global__ __launch_bounds__(1024) void k_transpose(
    const float* __restrict__ in, _Float16* __restrict__ out,
    const float* __restrict__ pm,
    const float* __restrict__ pw_w1, const float* __restrict__ pw_b1,
    const float* __restrict__ pw_w2, const float* __restrict__ pw_b2,
    const float* __restrict__ pw_w3, const float* __restrict__ pw_b3,
    const float* __restrict__ reg_w1, const float* __restrict__ reg_w2,
    float* __restrict__ proj_ws, float* __restrict__ tabw,
    _Float16* __restrict__ wh1, _Float16* __restrict__ wh2)
{
    __shared__ float s[32][33];
    const int tx = threadIdx.x, ty = threadIdx.y;
    const int tid = ty * 32 + tx;
    const int hw0 = blockIdx.x * 32;
    const int vb  = blockIdx.y;
    s[ty][tx] = in[(vb * 32 + ty) * HW_ + hw0 + tx];
    __syncthreads();
    if (tid < 256) {
        int hw = tid >> 3, q = tid & 7;
        h4 hv;
        #pragma unroll
        for (int i = 0; i < 4; ++i) hv[i] = (_Float16)s[q*4 + i][hw];
        *(h4*)(out + ((size_t)vb * HW_ + hw0 + hw) * 32 + q*4) = hv;
    }

    if (blockIdx.x != 0 || blockIdx.y != 0) return;

    // ---- fused former k_proj work (block (0,0) only; disjoint ws memory) ----
    if (tid < B_) {
        int b = tid;
        float C0[4][4], C0inv[4][4];
        combine_mat(pm + (b * V_ + 0) * 32, C0);
        invert4(C0, C0inv);
        for (int v = 1; v < V_; ++v) {
            float Cv[4][4];
            combine_mat(pm + (b * V_ + v) * 32, Cv);
            float* o = proj_ws + (b * 4 + (v - 1)) * 12;
            for (int r = 0; r < 3; ++r)
                for (int c = 0; c < 4; ++c) {
                    float sacc = 0.f;
                    for (int k = 0; k < 4; ++k) sacc += Cv[r][k] * C0inv[k][c];
                    o[r*4 + c] = sacc;
                }
        }
    }
    for (int i = tid; i < 36*16*8; i += 1024) {
        int ic = i & 7; int m = (i >> 3) & 15; int slot = i >> 7;
        int wx = slot & 3; int grp = slot >> 2;
        wh1[i] = (_Float16)((wx < 3 && m < 8) ? reg_w1[(m*8 + ic)*27 + grp*3 + wx] : 0.f);
    }
    for (int i = tid; i < 36*8; i += 1024) {
        int ic = i & 7; int slot = i >> 3;
        int wx = slot & 3; int grp = slot >> 2;
        wh2[i] = (_Float16)((wx < 3) ? reg_w2[ic*27 + grp*3 + wx] : 0.f);
    }
    float ent = (float)tid * (LN8_ / 1023.0f);
    float h2v[8];
    #pragma unroll
    for (int jj = 0; jj < 8; ++jj) h2v[jj] = pw_b2[jj];
    for (int k = 0; k < 16; ++k) {
        float h1 = fmaxf(ent * pw_w1[k] + pw_b1[k], 0.f);
        #pragma unroll
        for (int jj = 0; jj < 8; ++jj) h2v[jj] += pw_w2[jj*16 + k] * h1;
    }
    float o3 = pw_b3[0];
    #pragma unroll
    for (int jj = 0; jj < 8; ++jj) o3 += pw_w3[jj] * fmaxf(h2v[jj], 0.f);
    tabw[tid] = 1.f / (1.f + expf(-o3));
}

// ---------------- main fused kernel: depth-major lanes + block-cooperative band staging ----------
// grid (W/32, H, B), block 1024. wave wv: pixels {2wv,2wv+1} x 32 depths; lane = j*32+d.
// Phase 1: coords once -> scratch (overlays s_sim) + per-view bbox reduction.
// Phase 2: stage single-row bands (<=64 records) into conflict-free LDS.
// Phase 3: consume from LDS (global fallback if a view's band doesn't qualify).
// NOTE: no min-waves in launch_bounds — R8 showed forcing 8 waves/EU caps VGPR at 64,
// spills this kernel to scratch (+160MB HBM traffic/dispatch), and becomes the bottleneck.

struct C5 { float w00, w01, w10, w11; int xc0, xc1, yc0, yc1; };

__device__ inline C5 proj_coords(const float* __restrict__ P, float xf, float yf, float depth) {
    C5 c;
    float px = (P[0]*xf + P[1]*yf + P[2])  * depth + P[3];
    float py = (P[4]*xf + P[5]*yf + P[6])  * depth + P[7];
    float pz = (P[8]*xf + P[9]*yf + P[10]) * depth + P[11];
    float rz = __builtin_amdgcn_rcpf(pz);
    float xs = px * rz;
    float ys = py * rz;
    float xr = rintf(xs), yr = rintf(ys);
    xs = (fabsf(xs - xr) < 1e-4f) ? xr : xs;
    ys = (fabsf(ys - yr) < 1e-4f) ? yr : ys;
    float x0 = floorf(xs), y0 = floorf(ys);
    float wx1 = xs - x0,  wy1 = ys - y0;
    float wx0 = 1.f - wx1, wy0 = 1.f - wy1;
    bool vx0 = (x0 >= 0.f)     && (x0 <= (float)(W_-1));
    bool vx1 = (x0+1.f >= 0.f) && (x0+1.f <= (float)(W_-1));
    bool vy0 = (y0 >= 0.f)     && (y0 <= (float)(H_-1));
    bool vy1 = (y0+1.f >= 0.f) && (y0+1.f <= (float)(H_-1));
    c.xc0 = (int)fminf(fmaxf(x0,     0.f), (float)(W_-1));
    c.xc1 = (int)fminf(fmaxf(x0+1.f, 0.f), (float)(W_-1));
    c.yc0 = (int)fminf(fmaxf(y0,     0.f), (float)(H_-1));
    c.yc1 = (int)fminf(fmaxf(y0+1.f, 0.f), (float)(H_-1));
    c.w00 = (vx0 && vy0) ? (wx0 * wy0) : 0.f;
    c.w01 = (vx1 && vy0) ? (wx1 * wy0) : 0.f;
    c.w10 = (vx0 && vy1) ? (wx0 * wy1) : 0.f;
    c.w11 = (vx1 && vy1) ? (wx1 * wy1) : 0.f;
    return c;
}

__global__ __launch_bounds__(1024) void k_main(
    const _Float16* __restrict__ featT, // [VB][HW][32] fp16
    const float* __restrict__ depthv,   // [B][D][H][W]
    const float* __restrict__ proj_ws,
    const float* __restrict__ tabw,
    float* __restrict__ out_vw,         // [B][4][H][W]
    float* __restrict__ out_sim,        // [B][G][D][H][W] fp32
    _Float16* __restrict__ simh)        // [B][D][H][W][8] fp16
{
    const int tid = threadIdx.x;
    const int wv   = tid >> 6;
    const int lane = tid & 63;
    const int j    = lane >> 5;
    const int d    = lane & 31;
    const int pxl  = wv * 2 + j;
    const int w0 = blockIdx.x * 32;
    const int h  = blockIdx.y;
    const int b  = blockIdx.z;
    const int w  = w0 + pxl;
    const int p  = h * W_ + w;

    __shared__ float tab_s[1024];
    __shared__ float proj_s[48];
    __shared__ __align__(16) float s_sim[G_][32][33];        // scratch in phases 1-3, epilogue after
    __shared__ __align__(16) uint32_t stageu[4][1024];       // [view][granule(4)][x(64)][dword(4)]
    __shared__ float s_dep[32][33];
    __shared__ int fin[4][6];  // xmin, xmax, ymin, ymax, rowUniform, botNeeded

    tab_s[tid] = tabw[tid];
    if (tid < 48) proj_s[tid] = proj_ws[b * 48 + tid];
    { int dd = tid >> 5, pp = tid & 31;
      s_dep[dd][pp] = depthv[(b * D_ + dd) * HW_ + h * W_ + w0 + pp]; }
    if (tid < 24) {
        int vv = tid / 6, f = tid % 6;
        int val;
        if (f == 0 || f == 2) val = 0x7fffffff;
        else if (f == 1 || f == 3) val = (int)0x80000000;
        else if (f == 4) val = 1;
        else val = 0;
        fin[vv][f] = val;
    }
    __syncthreads();   // #1

    const float depth = s_dep[d][pxl];
    const float xf = (float)w, yf = (float)h;

    // -------- phase 1: coords + scratch + bbox reduction --------
    #pragma unroll
    for (int v = 1; v < V_; ++v) {
        C5 c = proj_coords(&proj_s[(v - 1) * 12], xf, yf, depth);
        uint32_t pk = (uint32_t)c.xc0 | ((uint32_t)c.xc1 << 16);
        h2 wp = { (_Float16)c.w00, (_Float16)c.w01 };
        uint32_t wpu = __builtin_bit_cast(uint32_t, wp);
        ((uint2*)s_sim)[(v - 1) * 1024 + tid] = make_uint2(pk, wpu);

        int xmn = c.xc0, xmx = c.xc1;
        #pragma unroll
        for (int k = 32; k >= 1; k >>= 1) {
            int a = __shfl_xor(xmn, k, 64); xmn = a < xmn ? a : xmn;
            int bmx = __shfl_xor(xmx, k, 64); xmx = bmx > xmx ? bmx : xmx;
        }
        int y0f = __shfl(c.yc0, 0, 64);
        bool rowu = __all(c.yc0 == y0f);
        bool bnw  = __any(c.w10 > 0.f || c.w11 > 0.f);
        if (lane == 0) {
            atomicMin(&fin[v-1][0], xmn);
            atomicMax(&fin[v-1][1], xmx);
            atomicMin(&fin[v-1][2], y0f);
            atomicMax(&fin[v-1][3], y0f);
            if (!rowu) fin[v-1][4] = 0;
            if (bnw)   fin[v-1][5] = 1;
        }
    }
    __syncthreads();   // #2

    // -------- phase 2: stage qualifying view bands (64 records, coalesced) --------
    #pragma unroll
    for (int v = 1; v < V_; ++v) {
        int fxmin = fin[v-1][0];
        int yrow  = fin[v-1][2];
        bool fast = fin[v-1][4] && !fin[v-1][5] &&
                    (fin[v-1][2] == fin[v-1][3]) && (fin[v-1][1] - fxmin < 64);
        if (fast) {
            int rec0 = yrow * W_ + fxmin;
            int rec  = rec0 + (tid >> 4);
            uint32_t val = 0u;
            if (rec < HW_) {   // guard: never read past this view's image
                const uint32_t* src = (const uint32_t*)featT +
                    ((size_t)(v * B_ + b) * HW_ + (size_t)rec0) * 16;
                val = src[tid];
            }
            stageu[v-1][((((tid >> 2) & 3) << 6) | (tid >> 4)) * 4 + (tid & 3)] = val;
        }
    }
    __syncthreads();   // #3

    // ref fragment (view 0)
    const h8* rp = (const h8*)(featT + ((size_t)b * HW_ + p) * 32);
    h8 r8[4];
    #pragma unroll
    for (int cc = 0; cc < 4; ++cc) r8[cc] = rp[cc];

    float simsum[G_];
    #pragma unroll
    for (int g = 0; g < G_; ++g) simsum[g] = 0.f;
    float wsum = 0.f;

    // -------- phase 3: consume --------
    #pragma unroll
    for (int v = 1; v < V_; ++v) {
        float sim[G_];
        #pragma unroll
        for (int g = 0; g < G_; ++g) sim[g] = 0.f;

        int fxmin = fin[v-1][0];
        bool fast = fin[v-1][4] && !fin[v-1][5] &&
                    (fin[v-1][2] == fin[v-1][3]) && (fin[v-1][1] - fxmin < 64);

        if (fast) {
            uint2 sv = ((const uint2*)s_sim)[(v - 1) * 1024 + tid];
            int xc0 = (int)(sv.x & 0xffffu), xc1 = (int)(sv.x >> 16);
            h2 wp = __builtin_bit_cast(h2, sv.y);
            bool top = __any(wp[0] > (_Float16)0.f || wp[1] > (_Float16)0.f);
            if (top) {
                h2 w00h = { wp[0], wp[0] };
                h2 w01h = { wp[1], wp[1] };
                const h8* sp = (const h8*)&stageu[v-1][0];
                int xr0 = xc0 - fxmin, xr1 = xc1 - fxmin;
                #pragma unroll
                for (int cc = 0; cc < 4; ++cc) {
                    h8 a = sp[cc*64 + xr0], bb = sp[cc*64 + xr1];
                    const h2* ap = (const h2*)&a;
                    const h2* bp = (const h2*)&bb;
                    const h2* rv2 = (const h2*)&r8[cc];
                    #pragma unroll
                    for (int jp = 0; jp < 4; ++jp) {
                        h2 fv = ap[jp] * w00h + bp[jp] * w01h;
                        int g = cc*2 + (jp >> 1);
                        sim[g] = fdot2f(fv, rv2[jp], sim[g]);
                    }
                }
            }
        } else {
            C5 c = proj_coords(&proj_s[(v - 1) * 12], xf, yf, depth);
            const _Float16* vbp = featT + (size_t)(v * B_ + b) * HW_ * 32;
            bool top = __any(c.w00 > 0.f || c.w01 > 0.f);
            bool bot = __any(c.w10 > 0.f || c.w11 > 0.f);
            if (top) {
                h2 w00h = { (_Float16)c.w00, (_Float16)c.w00 };
                h2 w01h = { (_Float16)c.w01, (_Float16)c.w01 };
                const h8* t00 = (const h8*)(vbp + (size_t)(c.yc0 * W_ + c.xc0) * 32);
                const h8* t01 = (const h8*)(vbp + (size_t)(c.yc0 * W_ + c.xc1) * 32);
                #pragma unroll
                for (int cc = 0; cc < 4; ++cc) {
                    h8 a = t00[cc], bb = t01[cc];
                    const h2* ap = (const h2*)&a;
                    const h2* bp = (const h2*)&bb;
                    const h2* rv2 = (const h2*)&r8[cc];
                    #pragma unroll
                    for (int jp = 0; jp < 4; ++jp) {
                        h2 fv = ap[jp] * w00h + bp[jp] * w01h;
                        int g = cc*2 + (jp >> 1);
                        sim[g] = fdot2f(fv, rv2[jp], sim[g]);
                    }
                }
            }
            if (bot) {
                h2 w10h = { (_Float16)c.w10, (_Float16)c.w10 };
                h2 w11h = { (_Float16)c.w11, (_Float16)c.w11 };
                const h8* t10 = (const h8*)(vbp + (size_t)(c.yc1 * W_ + c.xc0) * 32);
                const h8* t11 = (const h8*)(vbp + (size_t)(c.yc1 * W_ + c.xc1) * 32);
                #pragma unroll
                for (int cc = 0; cc < 4; ++cc) {
                    h8 cq = t10[cc], dq = t11[cc];
                    const h2* cp = (const h2*)&cq;
                    const h2* dp = (const h2*)&dq;
                    const h2* rv2 = (const h2*)&r8[cc];
                    #pragma unroll
                    for (int jp = 0; jp < 4; ++jp) {
                        h2 fv = cp[jp] * w10h + dp[jp] * w11h;
                        int g = cc*2 + (jp >> 1);
                        sim[g] = fdot2f(fv, rv2[jp], sim[g]);
                    }
                }
            }
        }

        #pragma unroll
        for (int g = 0; g < G_; ++g) sim[g] *= 0.25f;

        // entropy of softmax(sim)
        float m = sim[0];
        #pragma unroll
        for (int g = 1; g < G_; ++g) m = fmaxf(m, sim[g]);
        float es = 0.f, edot = 0.f;
        #pragma unroll
        for (int g = 0; g < G_; ++g) {
            float e = exp2f((sim[g] - m) * LOG2E_);
            es += e;
            edot = fmaf(e, sim[g], edot);
        }
        float inv_es = __builtin_amdgcn_rcpf(es);
        float ent = m + log2f(es) * LN2_ - edot * inv_es;

        // sigmoid(MLP(ent)) via table lerp
        float t = ent * (1023.0f / LN8_);
        t = fminf(fmaxf(t, 0.f), 1022.999f);
        int it = (int)t;
        float fr = t - (float)it;
        float lo = tab_s[it], hi = tab_s[it + 1];
        float sig = fmaf(hi - lo, fr, lo);

        // max over 32 depth lanes per pixel — shuffle only
        float mv = sig;
        #pragma unroll
        for (int k = 16; k >= 1; k >>= 1)
            mv = fmaxf(mv, __shfl_xor(mv, k, 64));
        if (d == 0)
            out_vw[(b * 4 + (v - 1)) * HW_ + p] = mv;

        #pragma unroll
        for (int g = 0; g < G_; ++g) simsum[g] = fmaf(sim[g], mv, simsum[g]);
        wsum += mv;
    }

    __syncthreads();   // #4 — scratch dead, s_sim reused for epilogue transpose

    float wn = __builtin_amdgcn_rcpf(wsum + 1e-6f);
    #pragma unroll
    for (int g = 0; g < G_; ++g) s_sim[g][d][pxl] = simsum[g] * wn;
    __syncthreads();   // #5

    const int tx = tid & 31;
    const int ty = tid >> 5;
    float* so = out_sim + (size_t)b * G_ * DHW_ + ty * HW_ + h * W_ + w0 + tx;
    h8 hv;
    #pragma unroll
    for (int g = 0; g < G_; ++g) {
        float val = s_sim[g][ty][tx];
        so[(size_t)g * DHW_] = val;
        hv[g] = (_Float16)val;
    }
    *(h8*)(simh + ((size_t)(b * D_ + ty) * HW_ + h * W_ + w0 + tx) * 8) = hv;
}

// ---------------- conv3d via MFMA implicit GEMM, wx-packed K-quads ----------------
__global__ __launch_bounds__(256) void k_conv1m(
    const _Float16* __restrict__ in,   // [B][D][H][W][8]
    const _Float16* __restrict__ wh,   // [36][16][8]
    const float* __restrict__ bias,    // [8]
    _Float16* __restrict__ outh)       // [B][D][H][W][8]
{
    __shared__ _Float16 halo[6*10*34*8 + 8];   // +16B zero pad for q=3 overread
    const int tid = threadIdx.x;
    const int w0 = blockIdx.x * 32;
    const int h0 = blockIdx.y * 8;
    const int z  = blockIdx.z;
    const int b  = z >> 3;
    const int d0 = (z & 7) * 4;

    for (int pos = tid; pos < 2040; pos += 256) {
        int wx = pos % 34; int r = pos / 34; int hy = r % 10; int dz = r / 10;
        int gw = w0 + wx - 1, gh = h0 + hy - 1, gd = d0 + dz - 1;
        uint4 val = make_uint4(0u, 0u, 0u, 0u);
        if (gw >= 0 && gw < W_ && gh >= 0 && gh < H_ && gd >= 0 && gd < D_)
            val = *(const uint4*)(in + (((size_t)(b*D_ + gd)*H_ + gh)*W_ + gw)*8);
        *(uint4*)(halo + pos*8) = val;
    }
    if (tid == 0) *(uint4*)(halo + 6*10*34*8) = make_uint4(0u, 0u, 0u, 0u);

    const int wave = tid >> 6, lane = tid & 63;
    const int n = lane & 15, q = lane >> 4;

    h8 afrag[9];
    #pragma unroll
    for (int grp = 0; grp < 9; ++grp)
        afrag[grp] = *(const h8*)(wh + ((grp*4 + q)*16 + n)*8);

    f4 binit;
    #pragma unroll
    for (int reg = 0; reg < 4; ++reg)
        binit[reg] = (q < 2) ? bias[q*4 + reg] : 0.f;

    __syncthreads();

    const int lane_off = (n + q) * 16;

    #pragma unroll
    for (int it = 0; it < 4; ++it) {
        int t = wave*4 + it;
        int h_row = t >> 1, whalf = t & 1;
        const char* base = (const char*)halo + h_row*544 + whalf*256 + lane_off;
        #pragma unroll
        for (int dout = 0; dout < 4; ++dout) {
            f4 acc = binit;
            #pragma unroll
            for (int dz = 0; dz < 3; ++dz) {
                #pragma unroll
                for (int hy = 0; hy < 3; ++hy) {
                    h8 bfrag = *(const h8*)(base + (((dout + dz)*10 + hy)*544));
                    acc = __builtin_amdgcn_mfma_f32_16x16x32_f16(afrag[dz*3 + hy], bfrag, acc, 0, 0, 0);
                }
            }
            if (q < 2) {
                h4 hv;
                #pragma unroll
                for (int reg = 0; reg < 4; ++reg) hv[reg] = (_Float16)fmaxf(acc[reg], 0.f);
                *(h4*)(outh + (((size_t)(b*D_ + d0 + dout)*H_ + h0 + h_row)*W_ + w0 + whalf*16 + n)*8 + q*4) = hv;
            }
        }
    }
}

__global__ __launch_bounds__(256) void k_conv2m(
    const _Float16* __restrict__ in,   // [B][D][H][W][8]
    const _Float16* __restrict__ wh,   // [36][8] (oc row 0 only)
    const float* __restrict__ bias,    // [1]
    float* __restrict__ out)           // [B][D][H][W]
{
    __shared__ _Float16 halo[6*10*34*8 + 8];
    const int tid = threadIdx.x;
    const int w0 = blockIdx.x * 32;
    const int h0 = blockIdx.y * 8;
    const int z  = blockIdx.z;
    const int b  = z >> 3;
    const int d0 = (z & 7) * 4;

    for (int pos = tid; pos < 2040; pos += 256) {
        int wx = pos % 34; int r = pos / 34; int hy = r % 10; int dz = r / 10;
        int gw = w0 + wx - 1, gh = h0 + hy - 1, gd = d0 + dz - 1;
        uint4 val = make_uint4(0u, 0u, 0u, 0u);
        if (gw >= 0 && gw < W_ && gh >= 0 && gh < H_ && gd >= 0 && gd < D_)
            val = *(const uint4*)(in + (((size_t)(b*D_ + gd)*H_ + gh)*W_ + gw)*8);
        *(uint4*)(halo + pos*8) = val;
    }
    if (tid == 0) *(uint4*)(halo + 6*10*34*8) = make_uint4(0u, 0u, 0u, 0u);

    const int wave = tid >> 6, lane = tid & 63;
    const int n = lane & 15, q = lane >> 4;

    h8 afrag[9];
    #pragma unroll
    for (int grp = 0; grp < 9; ++grp) {
        h8 a;
        #pragma unroll
        for (int e = 0; e < 8; ++e) a[e] = (_Float16)0.f;
        if (n == 0) a = *(const h8*)(wh + (grp*4 + q)*8);
        afrag[grp] = a;
    }
    const float b0 = bias[0];

    __syncthreads();

    const int lane_off = (n + q) * 16;

    #pragma unroll
    for (int it = 0; it < 4; ++it) {
        int t = wave*4 + it;
        int h_row = t >> 1, whalf = t & 1;
        const char* base = (const char*)halo + h_row*544 + whalf*256 + lane_off;
        #pragma unroll
        for (int dout = 0; dout < 4; ++dout) {
            f4 acc;
            acc[0] = (q == 0) ? b0 : 0.f;
            acc[1] = 0.f; acc[2] = 0.f; acc[3] = 0.f;
            #pragma unroll
            for (int dz = 0; dz < 3; ++dz) {
                #pragma unroll
                for (int hy = 0; hy < 3; ++hy) {
                    h8 bfrag = *(const h8*)(base + (((dout + dz)*10 + hy)*544));
                    acc = __builtin_amdgcn_mfma_f32_16x16x32_f16(afrag[dz*3 + hy], bfrag, acc, 0, 0, 0);
                }
            }
            if (q == 0)
                out[(((size_t)(b*D_ + d0 + dout)*H_ + h0 + h_row)*W_ + w0 + whalf*16 + n)] = acc[0];
        }
    }
}

// ---------------- final: softmax over D, depth, confidence ----------------
__global__ __launch_bounds__(256) void k_final(
    const float* __restrict__ pvp,
    const float* __restrict__ depthv,
    float* __restrict__ out_depth,
    float* __restrict__ out_conf)
{
    int i = blockIdx.x * 256 + threadIdx.x;
    if (i >= B_ * HW_) return;
    int b = i / HW_;
    int p = i - b * HW_;

    const float* pp = pvp + b * DHW_ + p;
    const float* dv = depthv + b * DHW_ + p;

    float x[D_];
    float m = -3.4e38f;
    #pragma unroll
    for (int d = 0; d < D_; ++d) { x[d] = pp[d * HW_]; m = fmaxf(m, x[d]); }
    float s = 0.f;
    #pragma unroll
    for (int d = 0; d < D_; ++d) { x[d] = exp2f((x[d] - m) * LOG2E_); s += x[d]; }
    float inv = 1.f / s;

    float dep = 0.f, fd = 0.f;
    #pragma unroll
    for (int d = 0; d < D_; ++d) {
        float pv = x[d] * inv;
        x[d] = pv;
        dep = fmaf(pv, dv[d * HW_], dep);
        fd  = fmaf(pv, (float)d, fd);
    }
    int di = (int)fd;
    di = di < 0 ? 0 : (di > D_ - 1 ? D_ - 1 : di);
    float conf = 0.f;
    #pragma unroll
    for (int k = 0; k < 4; ++k) {
        int idx = di - 1 + k;
        if (idx >= 0 && idx < D_) conf += x[idx];
    }
    out_depth[i] = dep;
    out_conf[i]  = conf;
}

// ---------------- launch ----------------
extern "C" void kernel_launch(void* const* d_in, const int* in_sizes, int n_in,
                              void* d_out, int out_size, void* d_ws, size_t ws_size,
                              hipStream_t stream) {
    const float* feat   = (const float*)d_in[0];
    const float* pm     = (const float*)d_in[1];
    const float* depthv = (const float*)d_in[2];
    const float* reg_w1 = (const float*)d_in[3];
    const float* reg_b1 = (const float*)d_in[4];
    const float* reg_w2 = (const float*)d_in[5];
    const float* reg_b2 = (const float*)d_in[6];
    const float* pw_w1  = (const float*)d_in[7];
    const float* pw_b1  = (const float*)d_in[8];
    const float* pw_w2  = (const float*)d_in[9];
    const float* pw_b2  = (const float*)d_in[10];
    const float* pw_w3  = (const float*)d_in[11];
    const float* pw_b3  = (const float*)d_in[12];

    float* out = (float*)d_out;
    float* out_depth = out;
    float* out_conf  = out + B_*HW_;
    float* out_vw    = out + 2*B_*HW_;
    float* out_pvp   = out_vw + B_*4*HW_;
    float* out_sim   = out_pvp + B_*DHW_;

    float* ws      = (float*)d_ws;
    float* proj_ws = ws;                        // 96 floats
    float* tabw    = ws + 128;                  // 1024 floats
    _Float16* wh1  = (_Float16*)(ws + 1152);    // 4608 halves -> ends 3456
    _Float16* wh2  = (_Float16*)(ws + 3456);    // 288 halves  -> ends 3600
    _Float16* featT = (_Float16*)(ws + 4736);   // 6.55M halves, dead after k_main
    _Float16* hidh  = (_Float16*)(ws + 4736);   // 10.49M halves, overwrites featT
    _Float16* simh  = (_Float16*)(ws + 4736 + 5242880); // 10.49M halves

    hipLaunchKernelGGL(k_transpose, dim3(HW_/32, V_*B_), dim3(32, 32), 0, stream,
                       feat, featT,
                       pm, pw_w1, pw_b1, pw_w2, pw_b2, pw_w3, pw_b3,
                       reg_w1, reg_w2, proj_ws, tabw, wh1, wh2);

    hipLaunchKernelGGL(k_main, dim3(W_/32, H_, B_), dim3(1024), 0, stream,
                       featT, depthv, proj_ws, tabw, out_vw, out_sim, simh);

    hipLaunchKernelGGL(k_conv1m, dim3(W_/32, H_/8, B_*D_/4), dim3(256), 0, stream,
                       simh, wh1, reg_b1, hidh);

    hipLaunchKernelGGL(k_conv2m, dim3(W_/32, H_/8, B_*D_/4), dim3(256), 0, stream,
                       hidh, wh2, reg_b2, out_pvp);

    hipLaunchKernelGGL(k_final, dim3((B_*HW_ + 255)/256), dim3(256), 0, stream,
                       out_pvp, depthv, out_depth, out_conf);
}

// Round 10
// 208.691 us; speedup vs baseline: 1.1085x; 1.1085x over previous
//
#include <hip/hip_runtime.h>
#include <hip/hip_bf16.h>
#include <hip/hip_fp16.h>

#define V_  5
#define B_  2
#define C_  32
#define H_  128
#define W_  160
#define D_  32
#define G_  8
#define HW_  (H_*W_)
#define DHW_ (D_*HW_)

#define LOG2E_ 1.4426950408889634f
#define LN2_   0.6931471805599453f
#define LN8_   2.0794415416798357f

typedef _Float16 h8 __attribute__((ext_vector_type(8)));
typedef _Float16 h4 __attribute__((ext_vector_type(4)));
typedef _Float16 h2 __attribute__((ext_vector_type(2)));
typedef float    f4 __attribute__((ext_vector_type(4)));

__device__ inline float fdot2f(h2 a, h2 b, float c) {
#if __has_builtin(__builtin_amdgcn_fdot2)
    return __builtin_amdgcn_fdot2(a, b, c, false);
#else
    return fmaf((float)a[0], (float)b[0], fmaf((float)a[1], (float)b[1], c));
#endif
}

// ws layout (floats):
//  [0..95]      proj
//  [128..1151]  mlp sigmoid table
//  [1152..3455] wh1 fp16 [36][16][8]  (slot=(dz*3+hy)*4+wx, wx==3 zero)
//  [3456..3599] wh2 fp16 [36][8]      (m==0 row only)
//  [4736 ..]    featT fp16 (13.1MB, dead after k_main) / hidh fp16 (21MB)
//  [4736+5242880 ..] simh fp16 (21MB)
//
// Session notes (measured):
//  - wall = k_main + ~147us fixed (harness reset memsets + small kernels); only k_main moves the wall.
//  - k_main structural attacks all failed: pixel-major remap (+10us), 2-stage view ILP (+0),
//    block-coop LDS band staging (+20us: phase barriers serialize staging latency).
//  - launch_bounds min-waves=8 caps VGPR at 64 -> scratch spill (+160MB HBM/dispatch). Never again.

__device__ inline void combine_mat(const float* m, float out[4][4]) {
    const float* ext = m;
    const float* K   = m + 16;
    for (int r = 0; r < 4; ++r)
        for (int c = 0; c < 4; ++c)
            out[r][c] = ext[r*4 + c];
    for (int r = 0; r < 3; ++r)
        for (int c = 0; c < 4; ++c) {
            float s = 0.f;
            for (int k = 0; k < 3; ++k) s += K[r*4 + k] * ext[k*4 + c];
            out[r][c] = s;
        }
}

__device__ inline void invert4(const float Ain[4][4], float Inv[4][4]) {
    float A[4][4];
    for (int r = 0; r < 4; ++r)
        for (int c = 0; c < 4; ++c) {
            A[r][c]   = Ain[r][c];
            Inv[r][c] = (r == c) ? 1.f : 0.f;
        }
    for (int k = 0; k < 4; ++k) {
        int p = k; float best = fabsf(A[k][k]);
        for (int r = k + 1; r < 4; ++r) {
            float v = fabsf(A[r][k]);
            if (v > best) { best = v; p = r; }
        }
        if (p != k) {
            for (int j = 0; j < 4; ++j) {
                float t = A[k][j]; A[k][j] = A[p][j]; A[p][j] = t;
                t = Inv[k][j]; Inv[k][j] = Inv[p][j]; Inv[p][j] = t;
            }
        }
        float dinv = 1.f / A[k][k];
        for (int j = 0; j < 4; ++j) { A[k][j] *= dinv; Inv[k][j] *= dinv; }
        for (int r = 0; r < 4; ++r) {
            if (r == k) continue;
            float f = A[r][k];
            for (int j = 0; j < 4; ++j) {
                A[r][j]  -= f * A[k][j];
                Inv[r][j] -= f * Inv[k][j];
            }
        }
    }
}

// ---------------- feature transpose (+ fused proj/table/weight-pack on block 0) ----------------
// [V][B][C][H][W] f32 -> [VB][HW][C] fp16
__global__ __launch_bounds__(1024) void k_transpose(
    const float* __restrict__ in, _Float16* __restrict__ out,
    const float* __restrict__ pm,
    const float* __restrict__ pw_w1, const float* __restrict__ pw_b1,
    const float* __restrict__ pw_w2, const float* __restrict__ pw_b2,
    const float* __restrict__ pw_w3, const float* __restrict__ pw_b3,
    const float* __restrict__ reg_w1, const float* __restrict__ reg_w2,
    float* __restrict__ proj_ws, float* __restrict__ tabw,
    _Float16* __restrict__ wh1, _Float16* __restrict__ wh2)
{
    __shared__ float s[32][33];
    const int tx = threadIdx.x, ty = threadIdx.y;
    const int tid = ty * 32 + tx;
    const int hw0 = blockIdx.x * 32;
    const int vb  = blockIdx.y;
    s[ty][tx] = in[(vb * 32 + ty) * HW_ + hw0 + tx];
    __syncthreads();
    if (tid < 256) {
        int hw = tid >> 3, q = tid & 7;
        h4 hv;
        #pragma unroll
        for (int i = 0; i < 4; ++i) hv[i] = (_Float16)s[q*4 + i][hw];
        *(h4*)(out + ((size_t)vb * HW_ + hw0 + hw) * 32 + q*4) = hv;
    }

    if (blockIdx.x != 0 || blockIdx.y != 0) return;

    // ---- fused former k_proj work (block (0,0) only; disjoint ws memory) ----
    if (tid < B_) {
        int b = tid;
        float C0[4][4], C0inv[4][4];
        combine_mat(pm + (b * V_ + 0) * 32, C0);
        invert4(C0, C0inv);
        for (int v = 1; v < V_; ++v) {
            float Cv[4][4];
            combine_mat(pm + (b * V_ + v) * 32, Cv);
            float* o = proj_ws + (b * 4 + (v - 1)) * 12;
            for (int r = 0; r < 3; ++r)
                for (int c = 0; c < 4; ++c) {
                    float sacc = 0.f;
                    for (int k = 0; k < 4; ++k) sacc += Cv[r][k] * C0inv[k][c];
                    o[r*4 + c] = sacc;
                }
        }
    }
    for (int i = tid; i < 36*16*8; i += 1024) {
        int ic = i & 7; int m = (i >> 3) & 15; int slot = i >> 7;
        int wx = slot & 3; int grp = slot >> 2;
        wh1[i] = (_Float16)((wx < 3 && m < 8) ? reg_w1[(m*8 + ic)*27 + grp*3 + wx] : 0.f);
    }
    for (int i = tid; i < 36*8; i += 1024) {
        int ic = i & 7; int slot = i >> 3;
        int wx = slot & 3; int grp = slot >> 2;
        wh2[i] = (_Float16)((wx < 3) ? reg_w2[ic*27 + grp*3 + wx] : 0.f);
    }
    float ent = (float)tid * (LN8_ / 1023.0f);
    float h2v[8];
    #pragma unroll
    for (int jj = 0; jj < 8; ++jj) h2v[jj] = pw_b2[jj];
    for (int k = 0; k < 16; ++k) {
        float h1 = fmaxf(ent * pw_w1[k] + pw_b1[k], 0.f);
        #pragma unroll
        for (int jj = 0; jj < 8; ++jj) h2v[jj] += pw_w2[jj*16 + k] * h1;
    }
    float o3 = pw_b3[0];
    #pragma unroll
    for (int jj = 0; jj < 8; ++jj) o3 += pw_w3[jj] * fmaxf(h2v[jj], 0.f);
    tabw[tid] = 1.f / (1.f + expf(-o3));
}

// ---------------- main fused kernel (depth-major lanes — proven layout) ----------------
// grid (W/32, H, B), block 1024. wave wv: pixels {2wv,2wv+1} x 32 depths; lane = j*32+d.
// VALU trim vs R6: ref fragment pre-scaled by 0.25 at load (exact fp16 exponent shift),
// removing the per-view sim[g]*=0.25 pass (32 muls/thread -> 4 pk-muls once).
__global__ __launch_bounds__(1024) void k_main(
    const _Float16* __restrict__ featT, // [VB][HW][32] fp16
    const float* __restrict__ depthv,   // [B][D][H][W]
    const float* __restrict__ proj_ws,
    const float* __restrict__ tabw,
    float* __restrict__ out_vw,         // [B][4][H][W]
    float* __restrict__ out_sim,        // [B][G][D][H][W] fp32
    _Float16* __restrict__ simh)        // [B][D][H][W][8] fp16
{
    const int tid = threadIdx.x;
    const int wv   = tid >> 6;
    const int lane = tid & 63;
    const int j    = lane >> 5;
    const int d    = lane & 31;
    const int pxl  = wv * 2 + j;
    const int w0 = blockIdx.x * 32;
    const int h  = blockIdx.y;
    const int b  = blockIdx.z;
    const int w  = w0 + pxl;
    const int p  = h * W_ + w;

    __shared__ float tab_s[1024];
    __shared__ float proj_s[48];
    __shared__ float s_sim[G_][32][33];

    tab_s[tid] = tabw[tid];
    if (tid < 48) proj_s[tid] = proj_ws[b * 48 + tid];
    __syncthreads();

    // ref fragment (view 0), pre-scaled by 0.25 (the /4 of the group-mean over C/G=4)
    const h8* rp = (const h8*)(featT + ((size_t)b * HW_ + p) * 32);
    h8 r8[4];
    #pragma unroll
    for (int cc = 0; cc < 4; ++cc) r8[cc] = rp[cc] * (_Float16)0.25f;

    const float depth = depthv[(b * D_ + d) * HW_ + p];
    const float xf = (float)w, yf = (float)h;

    float simsum[G_];
    #pragma unroll
    for (int g = 0; g < G_; ++g) simsum[g] = 0.f;
    float wsum = 0.f;

    for (int v = 1; v < V_; ++v) {
        const float* P = &proj_s[(v - 1) * 12];
        float px = (P[0]*xf + P[1]*yf + P[2])  * depth + P[3];
        float py = (P[4]*xf + P[5]*yf + P[6])  * depth + P[7];
        float pz = (P[8]*xf + P[9]*yf + P[10]) * depth + P[11];
        float rz = __builtin_amdgcn_rcpf(pz);
        float xs = px * rz;
        float ys = py * rz;

        // snap near-integer coords (<=1e-4 px shift; makes zero-weight rows exact)
        float xr = rintf(xs);
        float yr = rintf(ys);
        xs = (fabsf(xs - xr) < 1e-4f) ? xr : xs;
        ys = (fabsf(ys - yr) < 1e-4f) ? yr : ys;

        float x0 = floorf(xs), y0 = floorf(ys);
        float wx1 = xs - x0,  wy1 = ys - y0;
        float wx0 = 1.f - wx1, wy0 = 1.f - wy1;

        bool vx0 = (x0 >= 0.f)     && (x0 <= (float)(W_-1));
        bool vx1 = (x0+1.f >= 0.f) && (x0+1.f <= (float)(W_-1));
        bool vy0 = (y0 >= 0.f)     && (y0 <= (float)(H_-1));
        bool vy1 = (y0+1.f >= 0.f) && (y0+1.f <= (float)(H_-1));

        int xc0 = (int)fminf(fmaxf(x0,     0.f), (float)(W_-1));
        int xc1 = (int)fminf(fmaxf(x0+1.f, 0.f), (float)(W_-1));
        int yc0 = (int)fminf(fmaxf(y0,     0.f), (float)(H_-1));
        int yc1 = (int)fminf(fmaxf(y0+1.f, 0.f), (float)(H_-1));

        float w00 = (vx0 && vy0) ? (wx0 * wy0) : 0.f;
        float w01 = (vx1 && vy0) ? (wx1 * wy0) : 0.f;
        float w10 = (vx0 && vy1) ? (wx0 * wy1) : 0.f;
        float w11 = (vx1 && vy1) ? (wx1 * wy1) : 0.f;

        const _Float16* vbp = featT + (size_t)(v * B_ + b) * HW_ * 32;

        float sim[G_];
        #pragma unroll
        for (int g = 0; g < G_; ++g) sim[g] = 0.f;

        bool top = __any(w00 > 0.f || w01 > 0.f);
        bool bot = __any(w10 > 0.f || w11 > 0.f);

        if (top) {
            h2 w00h = { (_Float16)w00, (_Float16)w00 };
            h2 w01h = { (_Float16)w01, (_Float16)w01 };
            const h8* t00 = (const h8*)(vbp + (size_t)(yc0 * W_ + xc0) * 32);
            const h8* t01 = (const h8*)(vbp + (size_t)(yc0 * W_ + xc1) * 32);
            #pragma unroll
            for (int cc = 0; cc < 4; ++cc) {
                h8 a = t00[cc], bb = t01[cc];
                const h2* ap = (const h2*)&a;
                const h2* bp = (const h2*)&bb;
                const h2* rv2 = (const h2*)&r8[cc];
                #pragma unroll
                for (int jp = 0; jp < 4; ++jp) {
                    h2 fv = ap[jp] * w00h + bp[jp] * w01h;
                    int g = cc*2 + (jp >> 1);
                    sim[g] = fdot2f(fv, rv2[jp], sim[g]);
                }
            }
        }
        if (bot) {
            h2 w10h = { (_Float16)w10, (_Float16)w10 };
            h2 w11h = { (_Float16)w11, (_Float16)w11 };
            const h8* t10 = (const h8*)(vbp + (size_t)(yc1 * W_ + xc0) * 32);
            const h8* t11 = (const h8*)(vbp + (size_t)(yc1 * W_ + xc1) * 32);
            #pragma unroll
            for (int cc = 0; cc < 4; ++cc) {
                h8 cq = t10[cc], dq = t11[cc];
                const h2* cp = (const h2*)&cq;
                const h2* dp = (const h2*)&dq;
                const h2* rv2 = (const h2*)&r8[cc];
                #pragma unroll
                for (int jp = 0; jp < 4; ++jp) {
                    h2 fv = cp[jp] * w10h + dp[jp] * w11h;
                    int g = cc*2 + (jp >> 1);
                    sim[g] = fdot2f(fv, rv2[jp], sim[g]);
                }
            }
        }

        // entropy of softmax(sim): ent = m + ln(es) - (sum e*sim)/es
        float m = sim[0];
        #pragma unroll
        for (int g = 1; g < G_; ++g) m = fmaxf(m, sim[g]);
        float es = 0.f, edot = 0.f;
        #pragma unroll
        for (int g = 0; g < G_; ++g) {
            float e = exp2f((sim[g] - m) * LOG2E_);
            es += e;
            edot = fmaf(e, sim[g], edot);
        }
        float inv_es = __builtin_amdgcn_rcpf(es);
        float ent = m + log2f(es) * LN2_ - edot * inv_es;

        // sigmoid(MLP(ent)) via table lerp
        float t = ent * (1023.0f / LN8_);
        t = fminf(fmaxf(t, 0.f), 1022.999f);
        int it = (int)t;
        float fr = t - (float)it;
        float lo = tab_s[it], hi = tab_s[it + 1];
        float sig = fmaf(hi - lo, fr, lo);

        // max over 32 depth lanes per pixel — shuffle only
        float mv = sig;
        #pragma unroll
        for (int k = 16; k >= 1; k >>= 1)
            mv = fmaxf(mv, __shfl_xor(mv, k, 64));
        if (d == 0)
            out_vw[(b * 4 + (v - 1)) * HW_ + p] = mv;

        #pragma unroll
        for (int g = 0; g < G_; ++g) simsum[g] = fmaf(sim[g], mv, simsum[g]);
        wsum += mv;
    }

    float wn = __builtin_amdgcn_rcpf(wsum + 1e-6f);
    #pragma unroll
    for (int g = 0; g < G_; ++g) s_sim[g][d][pxl] = simsum[g] * wn;
    __syncthreads();

    const int tx = tid & 31;
    const int ty = tid >> 5;
    float* so = out_sim + (size_t)b * G_ * DHW_ + ty * HW_ + h * W_ + w0 + tx;
    h8 hv;
    #pragma unroll
    for (int g = 0; g < G_; ++g) {
        float val = s_sim[g][ty][tx];
        so[(size_t)g * DHW_] = val;
        hv[g] = (_Float16)val;
    }
    *(h8*)(simh + ((size_t)(b * D_ + ty) * HW_ + h * W_ + w0 + tx) * 8) = hv;
}

// ---------------- conv3d via MFMA implicit GEMM, wx-packed K-quads ----------------
__global__ __launch_bounds__(256) void k_conv1m(
    const _Float16* __restrict__ in,   // [B][D][H][W][8]
    const _Float16* __restrict__ wh,   // [36][16][8]
    const float* __restrict__ bias,    // [8]
    _Float16* __restrict__ outh)       // [B][D][H][W][8]
{
    __shared__ _Float16 halo[6*10*34*8 + 8];   // +16B zero pad for q=3 overread
    const int tid = threadIdx.x;
    const int w0 = blockIdx.x * 32;
    const int h0 = blockIdx.y * 8;
    const int z  = blockIdx.z;
    const int b  = z >> 3;
    const int d0 = (z & 7) * 4;

    for (int pos = tid; pos < 2040; pos += 256) {
        int wx = pos % 34; int r = pos / 34; int hy = r % 10; int dz = r / 10;
        int gw = w0 + wx - 1, gh = h0 + hy - 1, gd = d0 + dz - 1;
        uint4 val = make_uint4(0u, 0u, 0u, 0u);
        if (gw >= 0 && gw < W_ && gh >= 0 && gh < H_ && gd >= 0 && gd < D_)
            val = *(const uint4*)(in + (((size_t)(b*D_ + gd)*H_ + gh)*W_ + gw)*8);
        *(uint4*)(halo + pos*8) = val;
    }
    if (tid == 0) *(uint4*)(halo + 6*10*34*8) = make_uint4(0u, 0u, 0u, 0u);

    const int wave = tid >> 6, lane = tid & 63;
    const int n = lane & 15, q = lane >> 4;

    h8 afrag[9];
    #pragma unroll
    for (int grp = 0; grp < 9; ++grp)
        afrag[grp] = *(const h8*)(wh + ((grp*4 + q)*16 + n)*8);

    f4 binit;
    #pragma unroll
    for (int reg = 0; reg < 4; ++reg)
        binit[reg] = (q < 2) ? bias[q*4 + reg] : 0.f;

    __syncthreads();

    const int lane_off = (n + q) * 16;

    #pragma unroll
    for (int it = 0; it < 4; ++it) {
        int t = wave*4 + it;
        int h_row = t >> 1, whalf = t & 1;
        const char* base = (const char*)halo + h_row*544 + whalf*256 + lane_off;
        #pragma unroll
        for (int dout = 0; dout < 4; ++dout) {
            f4 acc = binit;
            #pragma unroll
            for (int dz = 0; dz < 3; ++dz) {
                #pragma unroll
                for (int hy = 0; hy < 3; ++hy) {
                    h8 bfrag = *(const h8*)(base + (((dout + dz)*10 + hy)*544));
                    acc = __builtin_amdgcn_mfma_f32_16x16x32_f16(afrag[dz*3 + hy], bfrag, acc, 0, 0, 0);
                }
            }
            if (q < 2) {
                h4 hv;
                #pragma unroll
                for (int reg = 0; reg < 4; ++reg) hv[reg] = (_Float16)fmaxf(acc[reg], 0.f);
                *(h4*)(outh + (((size_t)(b*D_ + d0 + dout)*H_ + h0 + h_row)*W_ + w0 + whalf*16 + n)*8 + q*4) = hv;
            }
        }
    }
}

__global__ __launch_bounds__(256) void k_conv2m(
    const _Float16* __restrict__ in,   // [B][D][H][W][8]
    const _Float16* __restrict__ wh,   // [36][8] (oc row 0 only)
    const float* __restrict__ bias,    // [1]
    float* __restrict__ out)           // [B][D][H][W]
{
    __shared__ _Float16 halo[6*10*34*8 + 8];
    const int tid = threadIdx.x;
    const int w0 = blockIdx.x * 32;
    const int h0 = blockIdx.y * 8;
    const int z  = blockIdx.z;
    const int b  = z >> 3;
    const int d0 = (z & 7) * 4;

    for (int pos = tid; pos < 2040; pos += 256) {
        int wx = pos % 34; int r = pos / 34; int hy = r % 10; int dz = r / 10;
        int gw = w0 + wx - 1, gh = h0 + hy - 1, gd = d0 + dz - 1;
        uint4 val = make_uint4(0u, 0u, 0u, 0u);
        if (gw >= 0 && gw < W_ && gh >= 0 && gh < H_ && gd >= 0 && gd < D_)
            val = *(const uint4*)(in + (((size_t)(b*D_ + gd)*H_ + gh)*W_ + gw)*8);
        *(uint4*)(halo + pos*8) = val;
    }
    if (tid == 0) *(uint4*)(halo + 6*10*34*8) = make_uint4(0u, 0u, 0u, 0u);

    const int wave = tid >> 6, lane = tid & 63;
    const int n = lane & 15, q = lane >> 4;

    h8 afrag[9];
    #pragma unroll
    for (int grp = 0; grp < 9; ++grp) {
        h8 a;
        #pragma unroll
        for (int e = 0; e < 8; ++e) a[e] = (_Float16)0.f;
        if (n == 0) a = *(const h8*)(wh + (grp*4 + q)*8);
        afrag[grp] = a;
    }
    const float b0 = bias[0];

    __syncthreads();

    const int lane_off = (n + q) * 16;

    #pragma unroll
    for (int it = 0; it < 4; ++it) {
        int t = wave*4 + it;
        int h_row = t >> 1, whalf = t & 1;
        const char* base = (const char*)halo + h_row*544 + whalf*256 + lane_off;
        #pragma unroll
        for (int dout = 0; dout < 4; ++dout) {
            f4 acc;
            acc[0] = (q == 0) ? b0 : 0.f;
            acc[1] = 0.f; acc[2] = 0.f; acc[3] = 0.f;
            #pragma unroll
            for (int dz = 0; dz < 3; ++dz) {
                #pragma unroll
                for (int hy = 0; hy < 3; ++hy) {
                    h8 bfrag = *(const h8*)(base + (((dout + dz)*10 + hy)*544));
                    acc = __builtin_amdgcn_mfma_f32_16x16x32_f16(afrag[dz*3 + hy], bfrag, acc, 0, 0, 0);
                }
            }
            if (q == 0)
                out[(((size_t)(b*D_ + d0 + dout)*H_ + h0 + h_row)*W_ + w0 + whalf*16 + n)] = acc[0];
        }
    }
}

// ---------------- final: softmax over D, depth, confidence ----------------
__global__ __launch_bounds__(256) void k_final(
    const float* __restrict__ pvp,
    const float* __restrict__ depthv,
    float* __restrict__ out_depth,
    float* __restrict__ out_conf)
{
    int i = blockIdx.x * 256 + threadIdx.x;
    if (i >= B_ * HW_) return;
    int b = i / HW_;
    int p = i - b * HW_;

    const float* pp = pvp + b * DHW_ + p;
    const float* dv = depthv + b * DHW_ + p;

    float x[D_];
    float m = -3.4e38f;
    #pragma unroll
    for (int d = 0; d < D_; ++d) { x[d] = pp[d * HW_]; m = fmaxf(m, x[d]); }
    float s = 0.f;
    #pragma unroll
    for (int d = 0; d < D_; ++d) { x[d] = exp2f((x[d] - m) * LOG2E_); s += x[d]; }
    float inv = 1.f / s;

    float dep = 0.f, fd = 0.f;
    #pragma unroll
    for (int d = 0; d < D_; ++d) {
        float pv = x[d] * inv;
        x[d] = pv;
        dep = fmaf(pv, dv[d * HW_], dep);
        fd  = fmaf(pv, (float)d, fd);
    }
    int di = (int)fd;
    di = di < 0 ? 0 : (di > D_ - 1 ? D_ - 1 : di);
    float conf = 0.f;
    #pragma unroll
    for (int k = 0; k < 4; ++k) {
        int idx = di - 1 + k;
        if (idx >= 0 && idx < D_) conf += x[idx];
    }
    out_depth[i] = dep;
    out_conf[i]  = conf;
}

// ---------------- launch ----------------
extern "C" void kernel_launch(void* const* d_in, const int* in_sizes, int n_in,
                              void* d_out, int out_size, void* d_ws, size_t ws_size,
                              hipStream_t stream) {
    const float* feat   = (const float*)d_in[0];
    const float* pm     = (const float*)d_in[1];
    const float* depthv = (const float*)d_in[2];
    const float* reg_w1 = (const float*)d_in[3];
    const float* reg_b1 = (const float*)d_in[4];
    const float* reg_w2 = (const float*)d_in[5];
    const float* reg_b2 = (const float*)d_in[6];
    const float* pw_w1  = (const float*)d_in[7];
    const float* pw_b1  = (const float*)d_in[8];
    const float* pw_w2  = (const float*)d_in[9];
    const float* pw_b2  = (const float*)d_in[10];
    const float* pw_w3  = (const float*)d_in[11];
    const float* pw_b3  = (const float*)d_in[12];

    float* out = (float*)d_out;
    float* out_depth = out;
    float* out_conf  = out + B_*HW_;
    float* out_vw    = out + 2*B_*HW_;
    float* out_pvp   = out_vw + B_*4*HW_;
    float* out_sim   = out_pvp + B_*DHW_;

    float* ws      = (float*)d_ws;
    float* proj_ws = ws;                        // 96 floats
    float* tabw    = ws + 128;                  // 1024 floats
    _Float16* wh1  = (_Float16*)(ws + 1152);    // 4608 halves -> ends 3456
    _Float16* wh2  = (_Float16*)(ws + 3456);    // 288 halves  -> ends 3600
    _Float16* featT = (_Float16*)(ws + 4736);   // 6.55M halves, dead after k_main
    _Float16* hidh  = (_Float16*)(ws + 4736);   // 10.49M halves, overwrites featT
    _Float16* simh  = (_Float16*)(ws + 4736 + 5242880); // 10.49M halves

    hipLaunchKernelGGL(k_transpose, dim3(HW_/32, V_*B_), dim3(32, 32), 0, stream,
                       feat, featT,
                       pm, pw_w1, pw_b1, pw_w2, pw_b2, pw_w3, pw_b3,
                       reg_w1, reg_w2, proj_ws, tabw, wh1, wh2);

    hipLaunchKernelGGL(k_main, dim3(W_/32, H_, B_), dim3(1024), 0, stream,
                       featT, depthv, proj_ws, tabw, out_vw, out_sim, simh);

    hipLaunchKernelGGL(k_conv1m, dim3(W_/32, H_/8, B_*D_/4), dim3(256), 0, stream,
                       simh, wh1, reg_b1, hidh);

    hipLaunchKernelGGL(k_conv2m, dim3(W_/32, H_/8, B_*D_/4), dim3(256), 0, stream,
                       hidh, wh2, reg_b2, out_pvp);

    hipLaunchKernelGGL(k_final, dim3((B_*HW_ + 255)/256), dim3(256), 0, stream,
                       out_pvp, depthv, out_depth, out_conf);
}